// Round 21
// baseline (88.576 us; speedup 1.0000x reference)
//
#include <hip/hip_runtime.h>
#include <hip/hip_bf16.h>
#include <stdint.h>
#include <math.h>

// SelfAttentionHead: B=4, T=4096, C=1024, D=128, fp32 in/out.
// wcvt -> proj (768-block LDS-staged GEMM, BK=64: 16 MFMA per barrier) ->
// attn (balanced chunk grid, swapped QK^T, 64-key stage, compact plds,
// 48KB LDS, launch_bounds(256,2) -> 3 blocks/CU no-spill) -> merge.

typedef __attribute__((ext_vector_type(4))) float f32x4;
typedef __attribute__((ext_vector_type(8))) short bf16x8;
typedef __attribute__((ext_vector_type(4))) unsigned short u16x4;
typedef __attribute__((ext_vector_type(2))) unsigned int u32x2;

#define NBATCH 4
#define NT 4096
#define NC 1024
#define ND 128
#define BT (NBATCH * NT)   // 16384
#define NSPLIT 8
#define KSPAN (NT / NSPLIT) // 512 keys per split slot

#define EXP2F(x) __builtin_amdgcn_exp2f(x)

__device__ __forceinline__ unsigned short f2bf(float f) {
  union { float f; uint32_t u; } v; v.f = f;
  uint32_t u = v.u;
  return (unsigned short)((u + 0x7FFFu + ((u >> 16) & 1u)) >> 16);
}

__device__ __forceinline__ float bf2f(unsigned short h) {
  union { uint32_t u; float f; } v; v.u = ((uint32_t)h) << 16;
  return v.f;
}

// pack two f32 -> packed 2xbf16 (RNE), single HW op
__device__ __forceinline__ unsigned int cvtpk(float a, float b) {
  unsigned int r;
  asm("v_cvt_pk_bf16_f32 %0, %1, %2" : "=v"(r) : "v"(a), "v"(b));
  return r;
}

// 8x f32 -> bf16x8 via 4 packed cvt ops (same RNE as f2bf)
__device__ __forceinline__ bf16x8 cvt8pk(const f32x4 a0, const f32x4 a1) {
  union { unsigned int u[4]; bf16x8 v; } r;
  r.u[0] = cvtpk(a0[0], a0[1]);
  r.u[1] = cvtpk(a0[2], a0[3]);
  r.u[2] = cvtpk(a1[0], a1[1]);
  r.u[3] = cvtpk(a1[2], a1[3]);
  return r.v;
}

// async global -> LDS, 16B per lane; dest = wave-uniform LDS base (+lane*16 HW)
__device__ __forceinline__ void g2lds16(const void* g, void* l) {
  __builtin_amdgcn_global_load_lds(
      (const __attribute__((address_space(1))) unsigned int*)g,
      (__attribute__((address_space(3))) unsigned int*)l, 16, 0, 0);
}

// ---------------------------------------------------------------------------
// Kernel 1: Wq/Wk/Wv [C][D] fp32 -> Wt [3][D][C] bf16 (transposed).
// Wk pre-scaled by log2(e)/sqrt(D): logits in exp2 units.
// ---------------------------------------------------------------------------
__global__ void wcvt_kernel(const float* __restrict__ Wq, const float* __restrict__ Wk,
                            const float* __restrict__ Wv, unsigned short* __restrict__ Wt) {
  const float CK = 0.12751744f;  // log2(e)/sqrt(128)
  int idx = blockIdx.x * blockDim.x + threadIdx.x;  // [0, 3*128*1024)
  int m = idx >> 17;
  int r = idx & 131071;
  int d = r >> 10;
  int c = r & 1023;
  const float* W = (m == 0) ? Wq : (m == 1) ? Wk : Wv;
  float v = W[c * ND + d];
  if (m == 1) v *= CK;
  Wt[idx] = f2bf(v);
}

// ---------------------------------------------------------------------------
// Kernel 2: fused QKV projection, BK=64. 768 blocks (256 mt x 3 nt), 4 waves.
// Per buffer: A [64][64] f32 (16K, 16 slots/row, s^=(row&7)) @0,
//             B [128][64] bf16 (16K, 8 slots/row, s^=(row&7)) @16384.
// 16 K-steps; per step each wave: 2 k-slices x (2 A-frags + 4 B-frags +
// 8 MFMA) = 16 MFMA per barrier. LDS 64 KB -> 2 blocks/CU.
// ---------------------------------------------------------------------------
__global__ __launch_bounds__(256, 2)
void proj_kernel(const float* __restrict__ x, const unsigned short* __restrict__ Wt,
                 unsigned short* __restrict__ Qb, unsigned short* __restrict__ Kb,
                 unsigned short* __restrict__ Vt) {
  __shared__ char smem[2][32768];

  int tid = threadIdx.x;
  int w = tid >> 6;
  int lane = tid & 63;
  int r16 = lane & 15;
  int h4 = lane >> 4;
  int wm = w & 1;
  int wn = w >> 1;

  int mt = blockIdx.x & 255;
  int nt = blockIdx.x >> 8;      // 0:Q 1:K 2:V

  const char* xg = (const char*)(x + (size_t)(mt * 64) * NC);
  const char* wg = (const char*)(Wt + (size_t)(nt * 128) * NC);

  f32x4 acc[2][4];
  #pragma unroll
  for (int m = 0; m < 2; ++m)
    #pragma unroll
    for (int n = 0; n < 4; ++n) acc[m][n] = (f32x4){0.f, 0.f, 0.f, 0.f};

  // staging: A = 1024 chunks of 16B, B = 1024 chunks; 8 issues/thread
  #define STAGE(buf, t)                                                          \
    {                                                                            \
      int c0 = (t) * 64;                                                         \
      _Pragma("unroll")                                                          \
      for (int j = 0; j < 4; ++j) {                                              \
        int c = j * 256 + tid, row = c >> 4, s = c & 15;                         \
        g2lds16(xg + (size_t)row * 4096 + c0 * 4 + ((s ^ (row & 7)) << 4),       \
                smem[buf] + (j * 256 + w * 64) * 16);                            \
      }                                                                          \
      _Pragma("unroll")                                                          \
      for (int j = 0; j < 4; ++j) {                                              \
        int c = j * 256 + tid, row = c >> 3, s = c & 7;                          \
        g2lds16(wg + (size_t)row * 2048 + c0 * 2 + ((s ^ (row & 7)) << 4),       \
                smem[buf] + 16384 + (j * 256 + w * 64) * 16);                    \
      }                                                                          \
    }

  STAGE(0, 0);
  __syncthreads();

  for (int t = 0; t < 16; ++t) {
    int cur = t & 1;
    if (t + 1 < 16) STAGE(cur ^ 1, t + 1);

    #pragma unroll
    for (int kk = 0; kk < 2; ++kk) {
      bf16x8 af[2];
      #pragma unroll
      for (int m = 0; m < 2; ++m) {
        int row = kk; (void)row;
        int arow = wm * 32 + m * 16 + r16;
        int s0 = (kk * 8 + h4 * 2) ^ (arow & 7);
        int s1 = (kk * 8 + h4 * 2 + 1) ^ (arow & 7);
        f32x4 a0 = *(const f32x4*)(smem[cur] + arow * 256 + s0 * 16);
        f32x4 a1 = *(const f32x4*)(smem[cur] + arow * 256 + s1 * 16);
        af[m] = cvt8pk(a0, a1);
      }
      __builtin_amdgcn_s_setprio(1);
      #pragma unroll
      for (int n = 0; n < 4; ++n) {
        int brow = wn * 64 + n * 16 + r16;
        int sb = (kk * 4 + h4) ^ (brow & 7);
        bf16x8 bfr = *(const bf16x8*)(smem[cur] + 16384 + brow * 128 + sb * 16);
        acc[0][n] = __builtin_amdgcn_mfma_f32_16x16x32_bf16(af[0], bfr, acc[0][n], 0, 0, 0);
        acc[1][n] = __builtin_amdgcn_mfma_f32_16x16x32_bf16(af[1], bfr, acc[1][n], 0, 0, 0);
      }
      __builtin_amdgcn_s_setprio(0);
    }
    __syncthreads();
  }
  #undef STAGE

  if (nt < 2) {
    unsigned short* dst = (nt == 0) ? Qb : Kb;
    #pragma unroll
    for (int m = 0; m < 2; ++m) {
      int t0 = mt * 64 + wm * 32 + m * 16 + h4 * 4;
      #pragma unroll
      for (int n = 0; n < 4; ++n) {
        int d = wn * 64 + n * 16 + r16;
        #pragma unroll
        for (int r = 0; r < 4; ++r)
          dst[(size_t)(t0 + r) * ND + d] = f2bf(acc[m][n][r]);
      }
    }
  } else {
    #pragma unroll
    for (int m = 0; m < 2; ++m) {
      int t0 = mt * 64 + wm * 32 + m * 16 + h4 * 4;
      int b = t0 >> 12;
      int tl = t0 & (NT - 1);
      #pragma unroll
      for (int n = 0; n < 4; ++n) {
        int d = wn * 64 + n * 16 + r16;
        u16x4 pk;
        #pragma unroll
        for (int r = 0; r < 4; ++r) pk[r] = f2bf(acc[m][n][r]);
        *(u16x4*)(Vt + (size_t)b * (ND * NT) + (size_t)d * NT + tl) = pk;
      }
    }
  }
}

// ---------------------------------------------------------------------------
// Kernel 3: flash attention (round-20 best, verbatim): 64-key stage, compact
// slot-swizzled plds, 48 KB LDS, launch_bounds(256,2) -> 3 blocks/CU.
// Balanced chunk grid + swapped QK^T.
// ---------------------------------------------------------------------------
__global__ __launch_bounds__(256, 2)
void attn_kernel(const unsigned short* __restrict__ Qb,
                 const unsigned short* __restrict__ Kb,
                 const unsigned short* __restrict__ Vt,
                 unsigned short* __restrict__ Opart, float* __restrict__ Mpart,
                 float* __restrict__ Lpart) {
  __shared__ unsigned short kbuf[64 * 128];   // [krow][d], swizzled (16 KB)
  __shared__ unsigned short vbuf[128 * 64];   // [d][t],   swizzled (16 KB)
  __shared__ unsigned short plds[4][2048];    // per-wave P [32][64], slot-XOR

  int wave = threadIdx.x >> 6;
  int lane = threadIdx.x & 63;
  int r16 = lane & 15;
  int h4 = lane >> 4;
  int h8 = h4 * 8;
  int a7 = r16 & 7;

  // ---- chunk id -> (b, qbt, s) ----
  int l = blockIdx.x;           // [0, 576)
  int b = l & 3;
  int u = l >> 2;               // [0, 144)
  int a = (int)((sqrtf(2.0f * (float)u + 1.0f) - 1.0f) * 0.5f);
  if (a < 0) a = 0;
  while (2 * (a + 1) * (a + 2) <= u) ++a;
  while (a > 0 && 2 * a * (a + 1) > u) --a;
  int rem = u - 2 * a * (a + 1);
  int apl = a + 1;
  int rr = rem / apl;
  int s = rem - rr * apl;
  int qbt = 4 * a + rr;

  int qb0 = qbt * 128;
  int z = s;
  int kstart = s << 9;
  int kend = min(qb0 + 128, kstart + KSPAN);

  int q0 = qb0 + wave * 32;

  const unsigned short* Qbb = Qb + (size_t)b * NT * ND;
  const unsigned short* Kbb = Kb + (size_t)b * NT * ND;
  const unsigned short* Vtb = Vt + (size_t)b * ND * NT;

  bf16x8 qf[2][4];
  #pragma unroll
  for (int f = 0; f < 2; ++f)
    #pragma unroll
    for (int dc = 0; dc < 4; ++dc)
      qf[f][dc] = *(const bf16x8*)(Qbb + (size_t)(q0 + f * 16 + r16) * ND + dc * 32 + h8);

  f32x4 accO[2][8];
  #pragma unroll
  for (int f = 0; f < 2; ++f)
    #pragma unroll
    for (int i = 0; i < 8; ++i) accO[f][i] = (f32x4){0.f, 0.f, 0.f, 0.f};
  float mr[2] = {-1e30f, -1e30f};   // per-lane: q = q0 + f*16 + r16
  float lr[2] = {0.f, 0.f};         // per-lane partial (this lane's 16 keys)

  for (int kv0 = kstart; kv0 < kend; kv0 += 64) {
    // ---- stage K [64][128] and V [128][64] into LDS (all 4 waves) ----
    #pragma unroll
    for (int i = 0; i < 4; ++i) {
      int e = i * 256 + wave * 64 + lane;
      int krow = e >> 4, ks = e & 15;
      const char* gk = (const char*)(Kbb + (size_t)(kv0 + krow) * ND)
                       + ((ks * 16) ^ ((krow & 7) << 4));
      g2lds16(gk, (char*)kbuf + (size_t)e * 16);
    }
    #pragma unroll
    for (int i = 0; i < 4; ++i) {
      int e = i * 256 + wave * 64 + lane;
      int vrow = e >> 3, vs = e & 7;
      const char* gv = (const char*)(Vtb + (size_t)vrow * NT + kv0)
                       + ((vs * 16) ^ ((vrow & 7) << 4));
      g2lds16(gv, (char*)vbuf + (size_t)e * 16);
    }
    __syncthreads();

    if (kv0 < q0 + 32) {       // wave-uniform: this wave has unmasked keys
      // ---- S^T = K Q^T (swapped operands) ----
      f32x4 sT[2][4];
      __builtin_amdgcn_s_setprio(1);
      #pragma unroll
      for (int kt = 0; kt < 4; ++kt) {
        sT[0][kt] = (f32x4){0.f, 0.f, 0.f, 0.f};
        sT[1][kt] = (f32x4){0.f, 0.f, 0.f, 0.f};
        int krow = kt * 16 + r16;
        #pragma unroll
        for (int dc = 0; dc < 4; ++dc) {
          int off = krow * 256 + ((dc * 64 + h4 * 16) ^ ((krow & 7) << 4));
          bf16x8 kf = *(const bf16x8*)((const char*)kbuf + off);
          sT[0][kt] = __builtin_amdgcn_mfma_f32_16x16x32_bf16(kf, qf[0][dc], sT[0][kt], 0, 0, 0);
          sT[1][kt] = __builtin_amdgcn_mfma_f32_16x16x32_bf16(kf, qf[1][dc], sT[1][kt], 0, 0, 0);
        }
      }
      __builtin_amdgcn_s_setprio(0);
      // lane holds S[key = kv0+kt*16+h4*4+r][q = q0+f*16+r16]

      // ---- mask + per-lane max over this lane's 16 keys ----
      float pmax[2] = {-3e38f, -3e38f};
      if (kv0 + 63 <= q0) {
        #pragma unroll
        for (int kt = 0; kt < 4; ++kt)
          #pragma unroll
          for (int f = 0; f < 2; ++f)
            #pragma unroll
            for (int r = 0; r < 4; ++r) pmax[f] = fmaxf(pmax[f], sT[f][kt][r]);
      } else {
        #pragma unroll
        for (int kt = 0; kt < 4; ++kt) {
          int kb = kv0 + kt * 16 + h4 * 4;
          #pragma unroll
          for (int f = 0; f < 2; ++f) {
            int q = q0 + f * 16 + r16;
            #pragma unroll
            for (int r = 0; r < 4; ++r) {
              float v = (kb + r <= q) ? sT[f][kt][r] : -3e38f;
              sT[f][kt][r] = v;
              pmax[f] = fmaxf(pmax[f], v);
            }
          }
        }
      }

      // ---- defer-max (T13): reduce + rescale ONLY if max grew > THR ----
      bool grow = (pmax[0] > mr[0] + 11.0f) || (pmax[1] > mr[1] + 11.0f);
      if (__any(grow)) {
        float sf[2], sfa[2][4];
        #pragma unroll
        for (int f = 0; f < 2; ++f) {
          pmax[f] = fmaxf(pmax[f], __shfl_xor(pmax[f], 16, 64));
          pmax[f] = fmaxf(pmax[f], __shfl_xor(pmax[f], 32, 64));
          float mn = fmaxf(mr[f], pmax[f]);
          sf[f] = EXP2F(mr[f] - mn);
          mr[f] = mn;
          lr[f] *= sf[f];
        }
        #pragma unroll
        for (int f = 0; f < 2; ++f)
          #pragma unroll
          for (int r = 0; r < 4; ++r) sfa[f][r] = __shfl(sf[f], h4 * 4 + r, 64);
        #pragma unroll
        for (int f = 0; f < 2; ++f)
          #pragma unroll
          for (int dt = 0; dt < 8; ++dt) {
            #pragma unroll
            for (int r = 0; r < 4; ++r) accO[f][dt][r] *= sfa[f][r];
          }
      }

      // ---- P = exp2(S - m); l accumulate; pack; slot-XOR b64 writes ----
      #pragma unroll
      for (int f = 0; f < 2; ++f) {
        int row = f * 16 + r16;
        #pragma unroll
        for (int kt = 0; kt < 4; ++kt) {
          float p0 = EXP2F(sT[f][kt][0] - mr[f]);
          float p1 = EXP2F(sT[f][kt][1] - mr[f]);
          float p2 = EXP2F(sT[f][kt][2] - mr[f]);
          float p3 = EXP2F(sT[f][kt][3] - mr[f]);
          lr[f] += (p0 + p1) + (p2 + p3);
          u32x2 pk;
          pk[0] = cvtpk(p0, p1);
          pk[1] = cvtpk(p2, p3);
          int slot = (2 * kt + (h4 >> 1)) ^ a7;
          *(u32x2*)&plds[wave][row * 64 + slot * 8 + (h4 & 1) * 4] = pk;
        }
      }

      // ---- O += P V ----
      __builtin_amdgcn_s_setprio(1);
      #pragma unroll
      for (int kc = 0; kc < 2; ++kc) {
        int sl = ((4 * kc + h4) ^ a7) * 8;
        bf16x8 pf0 = *(const bf16x8*)(&plds[wave][r16 * 64 + sl]);
        bf16x8 pf1 = *(const bf16x8*)(&plds[wave][(16 + r16) * 64 + sl]);
        #pragma unroll
        for (int dt = 0; dt < 8; ++dt) {
          int vrow = dt * 16 + r16;
          int off = vrow * 128 + ((kc * 64 + h4 * 16) ^ ((vrow & 7) << 4));
          bf16x8 vf = *(const bf16x8*)((const char*)vbuf + off);
          accO[0][dt] = __builtin_amdgcn_mfma_f32_16x16x32_bf16(pf0, vf, accO[0][dt], 0, 0, 0);
          accO[1][dt] = __builtin_amdgcn_mfma_f32_16x16x32_bf16(pf1, vf, accO[1][dt], 0, 0, 0);
        }
      }
      __builtin_amdgcn_s_setprio(0);
    }
    __syncthreads();
  }

  // ---- epilogue ----
  #pragma unroll
  for (int f = 0; f < 2; ++f) {
    lr[f] += __shfl_xor(lr[f], 16, 64);
    lr[f] += __shfl_xor(lr[f], 32, 64);
  }

  size_t pbase = ((size_t)z * NBATCH + b) * NT + q0;
  #pragma unroll
  for (int f = 0; f < 2; ++f)
    #pragma unroll
    for (int dt = 0; dt < 8; ++dt)
      #pragma unroll
      for (int r = 0; r < 4; ++r)
        Opart[(pbase + f * 16 + h4 * 4 + r) * ND + dt * 16 + r16] = f2bf(accO[f][dt][r]);
  if (h4 == 0) {
    #pragma unroll
    for (int f = 0; f < 2; ++f) {
      Mpart[pbase + f * 16 + r16] = mr[f];
      Lpart[pbase + f * 16 + r16] = lr[f];
    }
  }
}

// ---------------------------------------------------------------------------
// Kernel 4: merge valid splits (z <= q/KSPAN) -> final fp32 output
// ---------------------------------------------------------------------------
__global__ void merge_kernel(const unsigned short* __restrict__ Opart,
                             const float* __restrict__ Mpart,
                             const float* __restrict__ Lpart, float* __restrict__ out) {
  int idx = blockIdx.x * blockDim.x + threadIdx.x;  // [0, BT*16)
  int bq = idx >> 4;
  int dg = idx & 15;
  int q = bq & (NT - 1);
  int nz = (q >> 9) + 1;

  float M = -3e38f;
  #pragma unroll
  for (int zz = 0; zz < NSPLIT; ++zz)
    if (zz < nz) M = fmaxf(M, Mpart[(size_t)zz * BT + bq]);

  float denom = 0.f;
  float o[8] = {0.f, 0.f, 0.f, 0.f, 0.f, 0.f, 0.f, 0.f};
  #pragma unroll
  for (int zz = 0; zz < NSPLIT; ++zz) {
    if (zz < nz) {
      float e = EXP2F(Mpart[(size_t)zz * BT + bq] - M);
      denom += e * Lpart[(size_t)zz * BT + bq];
      bf16x8 ov = *(const bf16x8*)(Opart + ((size_t)zz * BT + bq) * ND + dg * 8);
      #pragma unroll
      for (int j = 0; j < 8; ++j) o[j] += e * bf2f((unsigned short)ov[j]);
    }
  }
  float inv = 1.0f / denom;
  f32x4 o0, o1;
  #pragma unroll
  for (int j = 0; j < 4; ++j) { o0[j] = o[j] * inv; o1[j] = o[4 + j] * inv; }
  float* dst = out + (size_t)bq * ND + dg * 8;
  *(f32x4*)dst = o0;
  *(f32x4*)(dst + 4) = o1;
}

// ---------------------------------------------------------------------------
extern "C" void kernel_launch(void* const* d_in, const int* in_sizes, int n_in,
                              void* d_out, int out_size, void* d_ws, size_t ws_size,
                              hipStream_t stream) {
  const float* x  = (const float*)d_in[0];
  const float* Wq = (const float*)d_in[1];
  const float* Wk = (const float*)d_in[2];
  const float* Wv = (const float*)d_in[3];

  char* ws = (char*)d_ws;
  // layout (bytes), total 47185920:
  //   Qb    @ 0        : 4194304
  //   Kb    @ 4194304  : 4194304
  //   Vt    @ 8388608  : 4194304
  //   Opart @ 12582912 : 33554432 (bf16)
  //   Mpart @ 46137344 : 524288
  //   Lpart @ 46661632 : 524288
  //   Wt    @ 12582912 : 786432  (ALIASES Opart: Wt dead before attn writes)
  unsigned short* Qb = (unsigned short*)ws;
  unsigned short* Kb = (unsigned short*)(ws + 4194304);
  unsigned short* Vt = (unsigned short*)(ws + 8388608);
  unsigned short* Opart = (unsigned short*)(ws + 12582912);
  float* Mpart = (float*)(ws + 46137344);
  float* Lpart = (float*)(ws + 46661632);
  unsigned short* Wt = (unsigned short*)(ws + 12582912);

  hipLaunchKernelGGL(wcvt_kernel, dim3(1536), dim3(256), 0, stream, Wq, Wk, Wv, Wt);
  hipLaunchKernelGGL(proj_kernel, dim3(768), dim3(256), 0, stream, x, Wt, Qb, Kb, Vt);
  hipLaunchKernelGGL(attn_kernel, dim3(576), dim3(256), 0, stream,
                     Qb, Kb, Vt, Opart, Mpart, Lpart);
  hipLaunchKernelGGL(merge_kernel, dim3(BT * 16 / 256), dim3(256), 0, stream,
                     Opart, Mpart, Lpart, (float*)d_out);
}

// Round 22
// 77.972 us; speedup vs baseline: 1.1360x; 1.1360x over previous
//
#include <hip/hip_runtime.h>
#include <hip/hip_bf16.h>
#include <stdint.h>
#include <math.h>

// SelfAttentionHead: B=4, T=4096, C=1024, D=128, fp32 in/out.
// Round-20 best configuration (78.2 us):
// wcvt -> proj (768-block LDS-staged GEMM, BK=32, cvt_pk A-fragments) ->
// attn (balanced chunk grid, swapped QK^T, 64-key stage, compact plds,
// 48KB LDS, launch_bounds(256,2) -> 3 blocks/CU no-spill) -> merge.

typedef __attribute__((ext_vector_type(4))) float f32x4;
typedef __attribute__((ext_vector_type(8))) short bf16x8;
typedef __attribute__((ext_vector_type(4))) unsigned short u16x4;
typedef __attribute__((ext_vector_type(2))) unsigned int u32x2;

#define NBATCH 4
#define NT 4096
#define NC 1024
#define ND 128
#define BT (NBATCH * NT)   // 16384
#define NSPLIT 8
#define KSPAN (NT / NSPLIT) // 512 keys per split slot

#define EXP2F(x) __builtin_amdgcn_exp2f(x)

__device__ __forceinline__ unsigned short f2bf(float f) {
  union { float f; uint32_t u; } v; v.f = f;
  uint32_t u = v.u;
  return (unsigned short)((u + 0x7FFFu + ((u >> 16) & 1u)) >> 16);
}

__device__ __forceinline__ float bf2f(unsigned short h) {
  union { uint32_t u; float f; } v; v.u = ((uint32_t)h) << 16;
  return v.f;
}

// pack two f32 -> packed 2xbf16 (RNE), single HW op
__device__ __forceinline__ unsigned int cvtpk(float a, float b) {
  unsigned int r;
  asm("v_cvt_pk_bf16_f32 %0, %1, %2" : "=v"(r) : "v"(a), "v"(b));
  return r;
}

// 8x f32 -> bf16x8 via 4 packed cvt ops (same RNE as f2bf)
__device__ __forceinline__ bf16x8 cvt8pk(const f32x4 a0, const f32x4 a1) {
  union { unsigned int u[4]; bf16x8 v; } r;
  r.u[0] = cvtpk(a0[0], a0[1]);
  r.u[1] = cvtpk(a0[2], a0[3]);
  r.u[2] = cvtpk(a1[0], a1[1]);
  r.u[3] = cvtpk(a1[2], a1[3]);
  return r.v;
}

// async global -> LDS, 16B per lane; dest = wave-uniform LDS base (+lane*16 HW)
__device__ __forceinline__ void g2lds16(const void* g, void* l) {
  __builtin_amdgcn_global_load_lds(
      (const __attribute__((address_space(1))) unsigned int*)g,
      (__attribute__((address_space(3))) unsigned int*)l, 16, 0, 0);
}

// ---------------------------------------------------------------------------
// Kernel 1: Wq/Wk/Wv [C][D] fp32 -> Wt [3][D][C] bf16 (transposed).
// Wk pre-scaled by log2(e)/sqrt(D): logits in exp2 units.
// ---------------------------------------------------------------------------
__global__ void wcvt_kernel(const float* __restrict__ Wq, const float* __restrict__ Wk,
                            const float* __restrict__ Wv, unsigned short* __restrict__ Wt) {
  const float CK = 0.12751744f;  // log2(e)/sqrt(128)
  int idx = blockIdx.x * blockDim.x + threadIdx.x;  // [0, 3*128*1024)
  int m = idx >> 17;
  int r = idx & 131071;
  int d = r >> 10;
  int c = r & 1023;
  const float* W = (m == 0) ? Wq : (m == 1) ? Wk : Wv;
  float v = W[c * ND + d];
  if (m == 1) v *= CK;
  Wt[idx] = f2bf(v);
}

// ---------------------------------------------------------------------------
// Kernel 2: fused QKV projection (768 blocks, 4 waves, fixed B-swizzle,
// cvt_pk A-fragments, BK=32).
// ---------------------------------------------------------------------------
__global__ __launch_bounds__(256, 3)
void proj_kernel(const float* __restrict__ x, const unsigned short* __restrict__ Wt,
                 unsigned short* __restrict__ Qb, unsigned short* __restrict__ Kb,
                 unsigned short* __restrict__ Vt) {
  __shared__ char smem[2][16384];

  int w = threadIdx.x >> 6;
  int lane = threadIdx.x & 63;
  int r16 = lane & 15;
  int h4 = lane >> 4;
  int wm = w & 1;
  int wn = w >> 1;

  int mt = blockIdx.x & 255;
  int nt = blockIdx.x >> 8;      // 0:Q 1:K 2:V

  const char* xg = (const char*)(x + (size_t)(mt * 64) * NC);
  const char* wg = (const char*)(Wt + (size_t)(nt * 128) * NC);

  f32x4 acc[2][4];
  #pragma unroll
  for (int m = 0; m < 2; ++m)
    #pragma unroll
    for (int n = 0; n < 4; ++n) acc[m][n] = (f32x4){0.f, 0.f, 0.f, 0.f};

  int cA0 = (w * 2 + 0) * 64 + lane;
  int cA1 = (w * 2 + 1) * 64 + lane;

  #define STAGE(buf, t)                                                          \
    {                                                                            \
      int c0 = (t) * 32;                                                         \
      {                                                                          \
        int c = cA0, row = c >> 3, s = c & 7;                                    \
        g2lds16(xg + (size_t)row * 4096 + c0 * 4 + ((s ^ (row & 7)) << 4),       \
                smem[buf] + (w * 2 + 0) * 1024);                                 \
      }                                                                          \
      {                                                                          \
        int c = cA1, row = c >> 3, s = c & 7;                                    \
        g2lds16(xg + (size_t)row * 4096 + c0 * 4 + ((s ^ (row & 7)) << 4),       \
                smem[buf] + (w * 2 + 1) * 1024);                                 \
      }                                                                          \
      {                                                                          \
        int c = cA0, row = c >> 2, s = c & 3;                                    \
        g2lds16(wg + (size_t)row * 2048 + c0 * 2 + ((s ^ ((row >> 1) & 3)) << 4),\
                smem[buf] + 8192 + (w * 2 + 0) * 1024);                          \
      }                                                                          \
      {                                                                          \
        int c = cA1, row = c >> 2, s = c & 3;                                    \
        g2lds16(wg + (size_t)row * 2048 + c0 * 2 + ((s ^ ((row >> 1) & 3)) << 4),\
                smem[buf] + 8192 + (w * 2 + 1) * 1024);                          \
      }                                                                          \
    }

  STAGE(0, 0);
  __syncthreads();

  for (int t = 0; t < 32; ++t) {
    int cur = t & 1;
    if (t + 1 < 32) STAGE(cur ^ 1, t + 1);

    bf16x8 af[2];
    #pragma unroll
    for (int m = 0; m < 2; ++m) {
      int row = wm * 32 + m * 16 + r16;
      f32x4 a0 = *(const f32x4*)(smem[cur] + row * 128 + (((h4 * 2) ^ (row & 7)) << 4));
      f32x4 a1 = *(const f32x4*)(smem[cur] + row * 128 + (((h4 * 2 + 1) ^ (row & 7)) << 4));
      af[m] = cvt8pk(a0, a1);
    }
    __builtin_amdgcn_s_setprio(1);
    #pragma unroll
    for (int n = 0; n < 4; ++n) {
      int brow = wn * 64 + n * 16 + r16;
      bf16x8 bfr = *(const bf16x8*)(smem[cur] + 8192 + brow * 64 +
                                    ((h4 ^ ((brow >> 1) & 3)) << 4));
      acc[0][n] = __builtin_amdgcn_mfma_f32_16x16x32_bf16(af[0], bfr, acc[0][n], 0, 0, 0);
      acc[1][n] = __builtin_amdgcn_mfma_f32_16x16x32_bf16(af[1], bfr, acc[1][n], 0, 0, 0);
    }
    __builtin_amdgcn_s_setprio(0);
    __syncthreads();
  }
  #undef STAGE

  if (nt < 2) {
    unsigned short* dst = (nt == 0) ? Qb : Kb;
    #pragma unroll
    for (int m = 0; m < 2; ++m) {
      int t0 = mt * 64 + wm * 32 + m * 16 + h4 * 4;
      #pragma unroll
      for (int n = 0; n < 4; ++n) {
        int d = wn * 64 + n * 16 + r16;
        #pragma unroll
        for (int r = 0; r < 4; ++r)
          dst[(size_t)(t0 + r) * ND + d] = f2bf(acc[m][n][r]);
      }
    }
  } else {
    #pragma unroll
    for (int m = 0; m < 2; ++m) {
      int t0 = mt * 64 + wm * 32 + m * 16 + h4 * 4;
      int b = t0 >> 12;
      int tl = t0 & (NT - 1);
      #pragma unroll
      for (int n = 0; n < 4; ++n) {
        int d = wn * 64 + n * 16 + r16;
        u16x4 pk;
        #pragma unroll
        for (int r = 0; r < 4; ++r) pk[r] = f2bf(acc[m][n][r]);
        *(u16x4*)(Vt + (size_t)b * (ND * NT) + (size_t)d * NT + tl) = pk;
      }
    }
  }
}

// ---------------------------------------------------------------------------
// Kernel 3: flash attention (round-20 best): 64-key stage, compact
// slot-swizzled plds, 48 KB LDS, launch_bounds(256,2) -> VGPR ~112 no-spill,
// HW fits 3 blocks/CU. Balanced chunk grid + swapped QK^T.
// ---------------------------------------------------------------------------
__global__ __launch_bounds__(256, 2)
void attn_kernel(const unsigned short* __restrict__ Qb,
                 const unsigned short* __restrict__ Kb,
                 const unsigned short* __restrict__ Vt,
                 unsigned short* __restrict__ Opart, float* __restrict__ Mpart,
                 float* __restrict__ Lpart) {
  __shared__ unsigned short kbuf[64 * 128];   // [krow][d], swizzled (16 KB)
  __shared__ unsigned short vbuf[128 * 64];   // [d][t],   swizzled (16 KB)
  __shared__ unsigned short plds[4][2048];    // per-wave P [32][64], slot-XOR

  int wave = threadIdx.x >> 6;
  int lane = threadIdx.x & 63;
  int r16 = lane & 15;
  int h4 = lane >> 4;
  int h8 = h4 * 8;
  int a7 = r16 & 7;

  // ---- chunk id -> (b, qbt, s) ----
  int l = blockIdx.x;           // [0, 576)
  int b = l & 3;
  int u = l >> 2;               // [0, 144)
  int a = (int)((sqrtf(2.0f * (float)u + 1.0f) - 1.0f) * 0.5f);
  if (a < 0) a = 0;
  while (2 * (a + 1) * (a + 2) <= u) ++a;
  while (a > 0 && 2 * a * (a + 1) > u) --a;
  int rem = u - 2 * a * (a + 1);
  int apl = a + 1;
  int rr = rem / apl;
  int s = rem - rr * apl;
  int qbt = 4 * a + rr;

  int qb0 = qbt * 128;
  int z = s;
  int kstart = s << 9;
  int kend = min(qb0 + 128, kstart + KSPAN);

  int q0 = qb0 + wave * 32;

  const unsigned short* Qbb = Qb + (size_t)b * NT * ND;
  const unsigned short* Kbb = Kb + (size_t)b * NT * ND;
  const unsigned short* Vtb = Vt + (size_t)b * ND * NT;

  bf16x8 qf[2][4];
  #pragma unroll
  for (int f = 0; f < 2; ++f)
    #pragma unroll
    for (int dc = 0; dc < 4; ++dc)
      qf[f][dc] = *(const bf16x8*)(Qbb + (size_t)(q0 + f * 16 + r16) * ND + dc * 32 + h8);

  f32x4 accO[2][8];
  #pragma unroll
  for (int f = 0; f < 2; ++f)
    #pragma unroll
    for (int i = 0; i < 8; ++i) accO[f][i] = (f32x4){0.f, 0.f, 0.f, 0.f};
  float mr[2] = {-1e30f, -1e30f};   // per-lane: q = q0 + f*16 + r16
  float lr[2] = {0.f, 0.f};         // per-lane partial (this lane's 16 keys)

  for (int kv0 = kstart; kv0 < kend; kv0 += 64) {
    // ---- stage K [64][128] and V [128][64] into LDS (all 4 waves) ----
    #pragma unroll
    for (int i = 0; i < 4; ++i) {
      int e = i * 256 + wave * 64 + lane;
      int krow = e >> 4, ks = e & 15;
      const char* gk = (const char*)(Kbb + (size_t)(kv0 + krow) * ND)
                       + ((ks * 16) ^ ((krow & 7) << 4));
      g2lds16(gk, (char*)kbuf + (size_t)e * 16);
    }
    #pragma unroll
    for (int i = 0; i < 4; ++i) {
      int e = i * 256 + wave * 64 + lane;
      int vrow = e >> 3, vs = e & 7;
      const char* gv = (const char*)(Vtb + (size_t)vrow * NT + kv0)
                       + ((vs * 16) ^ ((vrow & 7) << 4));
      g2lds16(gv, (char*)vbuf + (size_t)e * 16);
    }
    __syncthreads();

    if (kv0 < q0 + 32) {       // wave-uniform: this wave has unmasked keys
      // ---- S^T = K Q^T (swapped operands) ----
      f32x4 sT[2][4];
      __builtin_amdgcn_s_setprio(1);
      #pragma unroll
      for (int kt = 0; kt < 4; ++kt) {
        sT[0][kt] = (f32x4){0.f, 0.f, 0.f, 0.f};
        sT[1][kt] = (f32x4){0.f, 0.f, 0.f, 0.f};
        int krow = kt * 16 + r16;
        #pragma unroll
        for (int dc = 0; dc < 4; ++dc) {
          int off = krow * 256 + ((dc * 64 + h4 * 16) ^ ((krow & 7) << 4));
          bf16x8 kf = *(const bf16x8*)((const char*)kbuf + off);
          sT[0][kt] = __builtin_amdgcn_mfma_f32_16x16x32_bf16(kf, qf[0][dc], sT[0][kt], 0, 0, 0);
          sT[1][kt] = __builtin_amdgcn_mfma_f32_16x16x32_bf16(kf, qf[1][dc], sT[1][kt], 0, 0, 0);
        }
      }
      __builtin_amdgcn_s_setprio(0);
      // lane holds S[key = kv0+kt*16+h4*4+r][q = q0+f*16+r16]

      // ---- mask + per-lane max over this lane's 16 keys ----
      float pmax[2] = {-3e38f, -3e38f};
      if (kv0 + 63 <= q0) {
        #pragma unroll
        for (int kt = 0; kt < 4; ++kt)
          #pragma unroll
          for (int f = 0; f < 2; ++f)
            #pragma unroll
            for (int r = 0; r < 4; ++r) pmax[f] = fmaxf(pmax[f], sT[f][kt][r]);
      } else {
        #pragma unroll
        for (int kt = 0; kt < 4; ++kt) {
          int kb = kv0 + kt * 16 + h4 * 4;
          #pragma unroll
          for (int f = 0; f < 2; ++f) {
            int q = q0 + f * 16 + r16;
            #pragma unroll
            for (int r = 0; r < 4; ++r) {
              float v = (kb + r <= q) ? sT[f][kt][r] : -3e38f;
              sT[f][kt][r] = v;
              pmax[f] = fmaxf(pmax[f], v);
            }
          }
        }
      }

      // ---- defer-max (T13): reduce + rescale ONLY if max grew > THR ----
      bool grow = (pmax[0] > mr[0] + 11.0f) || (pmax[1] > mr[1] + 11.0f);
      if (__any(grow)) {
        float sf[2], sfa[2][4];
        #pragma unroll
        for (int f = 0; f < 2; ++f) {
          pmax[f] = fmaxf(pmax[f], __shfl_xor(pmax[f], 16, 64));
          pmax[f] = fmaxf(pmax[f], __shfl_xor(pmax[f], 32, 64));
          float mn = fmaxf(mr[f], pmax[f]);
          sf[f] = EXP2F(mr[f] - mn);
          mr[f] = mn;
          lr[f] *= sf[f];
        }
        #pragma unroll
        for (int f = 0; f < 2; ++f)
          #pragma unroll
          for (int r = 0; r < 4; ++r) sfa[f][r] = __shfl(sf[f], h4 * 4 + r, 64);
        #pragma unroll
        for (int f = 0; f < 2; ++f)
          #pragma unroll
          for (int dt = 0; dt < 8; ++dt) {
            #pragma unroll
            for (int r = 0; r < 4; ++r) accO[f][dt][r] *= sfa[f][r];
          }
      }

      // ---- P = exp2(S - m); l accumulate; pack; slot-XOR b64 writes ----
      #pragma unroll
      for (int f = 0; f < 2; ++f) {
        int row = f * 16 + r16;
        #pragma unroll
        for (int kt = 0; kt < 4; ++kt) {
          float p0 = EXP2F(sT[f][kt][0] - mr[f]);
          float p1 = EXP2F(sT[f][kt][1] - mr[f]);
          float p2 = EXP2F(sT[f][kt][2] - mr[f]);
          float p3 = EXP2F(sT[f][kt][3] - mr[f]);
          lr[f] += (p0 + p1) + (p2 + p3);
          u32x2 pk;
          pk[0] = cvtpk(p0, p1);
          pk[1] = cvtpk(p2, p3);
          int slot = (2 * kt + (h4 >> 1)) ^ a7;
          *(u32x2*)&plds[wave][row * 64 + slot * 8 + (h4 & 1) * 4] = pk;
        }
      }

      // ---- O += P V ----
      __builtin_amdgcn_s_setprio(1);
      #pragma unroll
      for (int kc = 0; kc < 2; ++kc) {
        int sl = ((4 * kc + h4) ^ a7) * 8;
        bf16x8 pf0 = *(const bf16x8*)(&plds[wave][r16 * 64 + sl]);
        bf16x8 pf1 = *(const bf16x8*)(&plds[wave][(16 + r16) * 64 + sl]);
        #pragma unroll
        for (int dt = 0; dt < 8; ++dt) {
          int vrow = dt * 16 + r16;
          int off = vrow * 128 + ((kc * 64 + h4 * 16) ^ ((vrow & 7) << 4));
          bf16x8 vf = *(const bf16x8*)((const char*)vbuf + off);
          accO[0][dt] = __builtin_amdgcn_mfma_f32_16x16x32_bf16(pf0, vf, accO[0][dt], 0, 0, 0);
          accO[1][dt] = __builtin_amdgcn_mfma_f32_16x16x32_bf16(pf1, vf, accO[1][dt], 0, 0, 0);
        }
      }
      __builtin_amdgcn_s_setprio(0);
    }
    __syncthreads();
  }

  // ---- epilogue ----
  #pragma unroll
  for (int f = 0; f < 2; ++f) {
    lr[f] += __shfl_xor(lr[f], 16, 64);
    lr[f] += __shfl_xor(lr[f], 32, 64);
  }

  size_t pbase = ((size_t)z * NBATCH + b) * NT + q0;
  #pragma unroll
  for (int f = 0; f < 2; ++f)
    #pragma unroll
    for (int dt = 0; dt < 8; ++dt)
      #pragma unroll
      for (int r = 0; r < 4; ++r)
        Opart[(pbase + f * 16 + h4 * 4 + r) * ND + dt * 16 + r16] = f2bf(accO[f][dt][r]);
  if (h4 == 0) {
    #pragma unroll
    for (int f = 0; f < 2; ++f) {
      Mpart[pbase + f * 16 + r16] = mr[f];
      Lpart[pbase + f * 16 + r16] = lr[f];
    }
  }
}

// ---------------------------------------------------------------------------
// Kernel 4: merge valid splits (z <= q/KSPAN) -> final fp32 output
// ---------------------------------------------------------------------------
__global__ void merge_kernel(const unsigned short* __restrict__ Opart,
                             const float* __restrict__ Mpart,
                             const float* __restrict__ Lpart, float* __restrict__ out) {
  int idx = blockIdx.x * blockDim.x + threadIdx.x;  // [0, BT*16)
  int bq = idx >> 4;
  int dg = idx & 15;
  int q = bq & (NT - 1);
  int nz = (q >> 9) + 1;

  float M = -3e38f;
  #pragma unroll
  for (int zz = 0; zz < NSPLIT; ++zz)
    if (zz < nz) M = fmaxf(M, Mpart[(size_t)zz * BT + bq]);

  float denom = 0.f;
  float o[8] = {0.f, 0.f, 0.f, 0.f, 0.f, 0.f, 0.f, 0.f};
  #pragma unroll
  for (int zz = 0; zz < NSPLIT; ++zz) {
    if (zz < nz) {
      float e = EXP2F(Mpart[(size_t)zz * BT + bq] - M);
      denom += e * Lpart[(size_t)zz * BT + bq];
      bf16x8 ov = *(const bf16x8*)(Opart + ((size_t)zz * BT + bq) * ND + dg * 8);
      #pragma unroll
      for (int j = 0; j < 8; ++j) o[j] += e * bf2f((unsigned short)ov[j]);
    }
  }
  float inv = 1.0f / denom;
  f32x4 o0, o1;
  #pragma unroll
  for (int j = 0; j < 4; ++j) { o0[j] = o[j] * inv; o1[j] = o[4 + j] * inv; }
  float* dst = out + (size_t)bq * ND + dg * 8;
  *(f32x4*)dst = o0;
  *(f32x4*)(dst + 4) = o1;
}

// ---------------------------------------------------------------------------
extern "C" void kernel_launch(void* const* d_in, const int* in_sizes, int n_in,
                              void* d_out, int out_size, void* d_ws, size_t ws_size,
                              hipStream_t stream) {
  const float* x  = (const float*)d_in[0];
  const float* Wq = (const float*)d_in[1];
  const float* Wk = (const float*)d_in[2];
  const float* Wv = (const float*)d_in[3];

  char* ws = (char*)d_ws;
  // layout (bytes), total 47185920:
  //   Qb    @ 0        : 4194304
  //   Kb    @ 4194304  : 4194304
  //   Vt    @ 8388608  : 4194304
  //   Opart @ 12582912 : 33554432 (bf16)
  //   Mpart @ 46137344 : 524288
  //   Lpart @ 46661632 : 524288
  //   Wt    @ 12582912 : 786432  (ALIASES Opart: Wt dead before attn writes)
  unsigned short* Qb = (unsigned short*)ws;
  unsigned short* Kb = (unsigned short*)(ws + 4194304);
  unsigned short* Vt = (unsigned short*)(ws + 8388608);
  unsigned short* Opart = (unsigned short*)(ws + 12582912);
  float* Mpart = (float*)(ws + 46137344);
  float* Lpart = (float*)(ws + 46661632);
  unsigned short* Wt = (unsigned short*)(ws + 12582912);

  hipLaunchKernelGGL(wcvt_kernel, dim3(1536), dim3(256), 0, stream, Wq, Wk, Wv, Wt);
  hipLaunchKernelGGL(proj_kernel, dim3(768), dim3(256), 0, stream, x, Wt, Qb, Kb, Vt);
  hipLaunchKernelGGL(attn_kernel, dim3(576), dim3(256), 0, stream,
                     Qb, Kb, Vt, Opart, Mpart, Lpart);
  hipLaunchKernelGGL(merge_kernel, dim3(BT * 16 / 256), dim3(256), 0, stream,
                     Opart, Mpart, Lpart, (float*)d_out);
}